// Round 1
// baseline (10913.223 us; speedup 1.0000x reference)
//
#include <hip/hip_runtime.h>
#include <hip/hip_bf16.h>

#define BATCH 4
#define TLEN 16384
#define CH 128        // RC = GC = SC
#define HC 64         // GC/2
#define TPRIME 10246
#define LDIFF 3069
#define NLAYERS 30
#define FC1C 2048
#define FC2C 256

// ---------------------------------------------------------------- first conv
__global__ __launch_bounds__(256) void k_first(const float* __restrict__ x,
                                               const float* __restrict__ Wf,
                                               float* __restrict__ h) {
    int b = blockIdx.y;
    int t = blockIdx.x * 256 + threadIdx.x;
    const float* xb = x + (size_t)b * TLEN;
    float xm = (t > 0) ? xb[t - 1] : 0.f;
    float x0 = xb[t];
    float xp = (t < TLEN - 1) ? xb[t + 1] : 0.f;
    float* hb = h + (size_t)b * CH * TLEN;
#pragma unroll 4
    for (int co = 0; co < CH; ++co) {
        float w0 = Wf[co * 3], w1 = Wf[co * 3 + 1], w2 = Wf[co * 3 + 2];
        hb[(size_t)co * TLEN + t] = w0 * xm + w1 * x0 + w2 * xp;
    }
}

// ------------------------------------------- transpose skip/res 1x1 weights
__global__ void k_prep(const float* __restrict__ Ws, const float* __restrict__ Wr,
                       float* __restrict__ WsT, float* __restrict__ WrT) {
    int idx = blockIdx.x * 256 + threadIdx.x;  // over NLAYERS*CH*HC
    if (idx >= NLAYERS * CH * HC) return;
    int l = idx / (CH * HC);
    int r = idx % (CH * HC);
    int co = r / HC, cz = r % HC;
    WsT[((size_t)l * HC + cz) * CH + co] = Ws[idx];
    WrT[((size_t)l * HC + cz) * CH + co] = Wr[idx];
}

// ---------------------------------------------------------------- layer kernel
// tile: 128 co x 32 t, 256 threads, 4x4 per-thread register tile.
// fused: dilated conv -> GLU -> skip accumulate + residual update.
__global__ __launch_bounds__(256) void k_layer(
    const float* __restrict__ h_in, float* __restrict__ h_out,
    float* __restrict__ skips,
    const float* __restrict__ Wd,    // [128][128][3] this layer
    const float* __restrict__ WsT,   // [64][128] this layer (transposed)
    const float* __restrict__ WrT,   // [64][128]
    int d) {
    __shared__ __align__(16) float smem[12288];  // 48 KB
    const int tid = threadIdx.x;
    const int b = blockIdx.y;
    const int t0 = blockIdx.x * 32;
    const int lm = tid & 31;   // co group (32)
    const int lh = tid >> 5;   // t group (8)
    const int co0 = lm * 4;
    const int tl0 = lh * 4;
    const float* hb = h_in + (size_t)b * CH * TLEN;

    float acc[4][4] = {};
    float(*WldsT)[132] = (float(*)[132])smem;               // 48 x 132 = 6336
    float(*hs)[16][32] = (float(*)[16][32])(smem + 6336);   // 3 x 16 x 32

#pragma unroll 1
    for (int ci0 = 0; ci0 < CH; ci0 += 16) {
        __syncthreads();
        for (int idx = tid; idx < 128 * 48; idx += 256) {
            int co = idx / 48, j = idx % 48;
            WldsT[j][co] = Wd[co * (CH * 3) + ci0 * 3 + j];
        }
        for (int idx = tid; idx < 3 * 16 * 32; idx += 256) {
            int k = idx >> 9;
            int r = idx & 511;
            int ci = r >> 5, tt = r & 31;
            int tg = t0 + tt + (k - 1) * d;
            float v = 0.f;
            if ((unsigned)tg < TLEN) v = hb[(size_t)(ci0 + ci) * TLEN + tg];
            hs[k][ci][tt] = v;
        }
        __syncthreads();
#pragma unroll
        for (int j = 0; j < 48; ++j) {
            const int ci = j / 3, k = j - 3 * ci;
            const float4 a4 = *(const float4*)&WldsT[j][co0];
            const float4 b4 = *(const float4*)&hs[k][ci][tl0];
            const float av[4] = {a4.x, a4.y, a4.z, a4.w};
            const float bv[4] = {b4.x, b4.y, b4.z, b4.w};
#pragma unroll
            for (int i = 0; i < 4; ++i)
#pragma unroll
                for (int jj = 0; jj < 4; ++jj) acc[i][jj] += av[i] * bv[jj];
        }
    }

    // ---- epilogue: g -> LDS, GLU, skip/res GEMMs (K=64)
    __syncthreads();
    float(*gbuf)[36] = (float(*)[36])smem;                // 128 x 36 = 4608
    float(*zbuf)[36] = (float(*)[36])(smem + 4608);       // 64 x 36 = 2304
    float(*w2s)[132] = (float(*)[132])(smem + 6912);      // 16 x 132 = 2112
    float(*w2r)[132] = (float(*)[132])(smem + 9024);      // 16 x 132
#pragma unroll
    for (int i = 0; i < 4; ++i) {
        float4 v = make_float4(acc[i][0], acc[i][1], acc[i][2], acc[i][3]);
        *(float4*)&gbuf[co0 + i][tl0] = v;
    }
    __syncthreads();
#pragma unroll
    for (int r = 0; r < 8; ++r) {
        int id = r * 256 + tid;  // lanes contiguous in t
        int c = id >> 5, tt = id & 31;
        float a = gbuf[c][tt];
        float g2 = gbuf[c + 64][tt];
        float th = tanhf(a);
        float sg = 1.f / (1.f + __expf(-g2));
        zbuf[c][tt] = th * sg;
    }
    float accS[4][4] = {}, accR[4][4] = {};
#pragma unroll 1
    for (int czc = 0; czc < HC; czc += 16) {
        __syncthreads();
        for (int idx = tid; idx < 16 * 128; idx += 256) {
            int cz = idx >> 7, co = idx & 127;
            w2s[cz][co] = WsT[(size_t)(czc + cz) * CH + co];
            w2r[cz][co] = WrT[(size_t)(czc + cz) * CH + co];
        }
        __syncthreads();
#pragma unroll
        for (int cz = 0; cz < 16; ++cz) {
            const float4 z4 = *(const float4*)&zbuf[czc + cz][tl0];
            const float4 s4 = *(const float4*)&w2s[cz][co0];
            const float4 r4 = *(const float4*)&w2r[cz][co0];
            const float zv[4] = {z4.x, z4.y, z4.z, z4.w};
            const float sv[4] = {s4.x, s4.y, s4.z, s4.w};
            const float rv[4] = {r4.x, r4.y, r4.z, r4.w};
#pragma unroll
            for (int i = 0; i < 4; ++i)
#pragma unroll
                for (int jj = 0; jj < 4; ++jj) {
                    accS[i][jj] += sv[i] * zv[jj];
                    accR[i][jj] += rv[i] * zv[jj];
                }
        }
    }
    const float scale = 0.70710678118654752f;
    float* hob = h_out + (size_t)b * CH * TLEN;
#pragma unroll
    for (int i = 0; i < 4; ++i) {
        int co = co0 + i;
        const float4 hi = *(const float4*)&hb[(size_t)co * TLEN + t0 + tl0];
        float4 ho;
        ho.x = (hi.x + accR[i][0]) * scale;
        ho.y = (hi.y + accR[i][1]) * scale;
        ho.z = (hi.z + accR[i][2]) * scale;
        ho.w = (hi.w + accR[i][3]) * scale;
        *(float4*)&hob[(size_t)co * TLEN + t0 + tl0] = ho;
#pragma unroll
        for (int jj = 0; jj < 4; ++jj) {
            int ts = t0 + tl0 + jj - LDIFF;
            if ((unsigned)ts < TPRIME)
                skips[((size_t)b * CH + co) * TPRIME + ts] += accS[i][jj];
        }
    }
}

// ---------------------------------------------------------------- fc1 (relu in, relu out, bf16 out)
__global__ __launch_bounds__(256) void k_fc1(const float* __restrict__ skips,
                                             const float* __restrict__ W,  // [2048][128][3]
                                             __hip_bfloat16* __restrict__ y1) {
    __shared__ __align__(16) float smem[7872];
    const int tid = threadIdx.x;
    const int b = blockIdx.z;
    const int cob = blockIdx.y * 128;
    const int t0 = blockIdx.x * 32;
    const int lm = tid & 31, lh = tid >> 5;
    const int co0 = lm * 4, tl0 = lh * 4;
    const float* sb = skips + (size_t)b * CH * TPRIME;
    float acc[4][4] = {};
    float(*WldsT)[132] = (float(*)[132])smem;
    float(*hs)[16][32] = (float(*)[16][32])(smem + 6336);
#pragma unroll 1
    for (int ci0 = 0; ci0 < CH; ci0 += 16) {
        __syncthreads();
        for (int idx = tid; idx < 128 * 48; idx += 256) {
            int co = idx / 48, j = idx % 48;
            WldsT[j][co] = W[(size_t)(cob + co) * (CH * 3) + ci0 * 3 + j];
        }
        for (int idx = tid; idx < 1536; idx += 256) {
            int k = idx >> 9;
            int r = idx & 511;
            int ci = r >> 5, tt = r & 31;
            int tg = t0 + tt + (k - 1);
            float v = 0.f;
            if ((unsigned)tg < TPRIME) {
                v = sb[(size_t)(ci0 + ci) * TPRIME + tg];
                v = v > 0.f ? v : 0.f;  // relu on input
            }
            hs[k][ci][tt] = v;
        }
        __syncthreads();
#pragma unroll
        for (int j = 0; j < 48; ++j) {
            const int ci = j / 3, k = j - 3 * ci;
            const float4 a4 = *(const float4*)&WldsT[j][co0];
            const float4 b4 = *(const float4*)&hs[k][ci][tl0];
            const float av[4] = {a4.x, a4.y, a4.z, a4.w};
            const float bv[4] = {b4.x, b4.y, b4.z, b4.w};
#pragma unroll
            for (int i = 0; i < 4; ++i)
#pragma unroll
                for (int jj = 0; jj < 4; ++jj) acc[i][jj] += av[i] * bv[jj];
        }
    }
    __hip_bfloat16* yb = y1 + ((size_t)b * FC1C + cob) * TPRIME;
#pragma unroll
    for (int i = 0; i < 4; ++i)
#pragma unroll
        for (int jj = 0; jj < 4; ++jj) {
            int tg = t0 + tl0 + jj;
            if (tg < TPRIME) {
                float v = acc[i][jj];
                v = v > 0.f ? v : 0.f;
                yb[(size_t)(co0 + i) * TPRIME + tg] = __float2bfloat16(v);
            }
        }
}

// ---------------------------------------------------------------- fc2 + fused 1x1 head (atomic)
__global__ __launch_bounds__(256) void k_fc2(const __hip_bfloat16* __restrict__ y1,
                                             const float* __restrict__ W,  // [256][2048][3]
                                             const float* __restrict__ Wlast,
                                             float* __restrict__ out) {
    __shared__ __align__(16) float smem[7872];
    __shared__ float red[32];
    const int tid = threadIdx.x;
    const int b = blockIdx.z;
    const int cob = blockIdx.y * 128;
    const int t0 = blockIdx.x * 32;
    const int lm = tid & 31, lh = tid >> 5;
    const int co0 = lm * 4, tl0 = lh * 4;
    const __hip_bfloat16* yb = y1 + (size_t)b * FC1C * TPRIME;
    float acc[4][4] = {};
    float(*WldsT)[132] = (float(*)[132])smem;
    float(*hs)[16][32] = (float(*)[16][32])(smem + 6336);
#pragma unroll 1
    for (int ci0 = 0; ci0 < FC1C; ci0 += 16) {
        __syncthreads();
        for (int idx = tid; idx < 128 * 48; idx += 256) {
            int co = idx / 48, j = idx % 48;
            WldsT[j][co] = W[(size_t)(cob + co) * (FC1C * 3) + ci0 * 3 + j];
        }
        for (int idx = tid; idx < 1536; idx += 256) {
            int k = idx >> 9;
            int r = idx & 511;
            int ci = r >> 5, tt = r & 31;
            int tg = t0 + tt + (k - 1);
            float v = 0.f;
            if ((unsigned)tg < TPRIME)
                v = __bfloat162float(yb[(size_t)(ci0 + ci) * TPRIME + tg]);
            hs[k][ci][tt] = v;
        }
        __syncthreads();
#pragma unroll
        for (int j = 0; j < 48; ++j) {
            const int ci = j / 3, k = j - 3 * ci;
            const float4 a4 = *(const float4*)&WldsT[j][co0];
            const float4 b4 = *(const float4*)&hs[k][ci][tl0];
            const float av[4] = {a4.x, a4.y, a4.z, a4.w};
            const float bv[4] = {b4.x, b4.y, b4.z, b4.w};
#pragma unroll
            for (int i = 0; i < 4; ++i)
#pragma unroll
                for (int jj = 0; jj < 4; ++jj) acc[i][jj] += av[i] * bv[jj];
        }
    }
    // fused final 1x1: partial over this block's 128 channels, reduce in LDS
    if (tid < 32) red[tid] = 0.f;
    __syncthreads();
    float wl[4];
#pragma unroll
    for (int i = 0; i < 4; ++i) wl[i] = Wlast[cob + co0 + i];
#pragma unroll
    for (int jj = 0; jj < 4; ++jj) {
        float s = wl[0] * acc[0][jj] + wl[1] * acc[1][jj] + wl[2] * acc[2][jj] +
                  wl[3] * acc[3][jj];
        atomicAdd(&red[tl0 + jj], s);
    }
    __syncthreads();
    if (tid < 32) {
        int tg = t0 + tid;
        if (tg < TPRIME) atomicAdd(&out[(size_t)b * TPRIME + tg], red[tid]);
    }
}

// ---------------------------------------------------------------- bias init
__global__ void k_bias(float* __restrict__ out, const float* __restrict__ bl) {
    int i = blockIdx.x * 256 + threadIdx.x;
    if (i < BATCH * TPRIME) out[i] = bl[0];
}

extern "C" void kernel_launch(void* const* d_in, const int* in_sizes, int n_in,
                              void* d_out, int out_size, void* d_ws, size_t ws_size,
                              hipStream_t stream) {
    const float* x = (const float*)d_in[0];
    const float* Wf = (const float*)d_in[1];
    const float* Wdil = (const float*)d_in[2];
    const float* Wskip = (const float*)d_in[3];
    const float* Wres = (const float*)d_in[4];
    const float* Wfc1 = (const float*)d_in[5];
    const float* Wfc2 = (const float*)d_in[6];
    const float* Wlast = (const float*)d_in[7];
    const float* blast = (const float*)d_in[8];
    float* out = (float*)d_out;

    char* ws = (char*)d_ws;
    const size_t skips_b = (size_t)BATCH * CH * TPRIME * 4;          // 20.98 MB
    const size_t wt_b = (size_t)NLAYERS * HC * CH * 4;               // 0.98 MB
    const size_t h_b = (size_t)BATCH * CH * TLEN * 4;                // 33.55 MB
    float* skips = (float*)ws;
    float* WsT = (float*)(ws + skips_b);
    float* WrT = (float*)(ws + skips_b + wt_b);
    char* big = ws + skips_b + 2 * wt_b;
    float* hA = (float*)big;                 // layers phase
    float* hB = (float*)(big + h_b);
    __hip_bfloat16* y1 = (__hip_bfloat16*)big;  // head phase (aliases hA/hB, dead by then)

    hipMemsetAsync(skips, 0, skips_b, stream);
    k_prep<<<(NLAYERS * CH * HC + 255) / 256, 256, 0, stream>>>(Wskip, Wres, WsT, WrT);
    k_first<<<dim3(TLEN / 256, BATCH), 256, 0, stream>>>(x, Wf, hA);

    float* hin = hA;
    float* hout = hB;
    for (int l = 0; l < NLAYERS; ++l) {
        int d = 1 << (l % 10);
        k_layer<<<dim3(TLEN / 32, BATCH), 256, 0, stream>>>(
            hin, hout, skips, Wdil + (size_t)l * CH * CH * 3,
            WsT + (size_t)l * HC * CH, WrT + (size_t)l * HC * CH, d);
        float* tmp = hin; hin = hout; hout = tmp;
    }

    k_bias<<<(BATCH * TPRIME + 255) / 256, 256, 0, stream>>>(out, blast);
    k_fc1<<<dim3((TPRIME + 31) / 32, FC1C / 128, BATCH), 256, 0, stream>>>(skips, Wfc1, y1);
    k_fc2<<<dim3((TPRIME + 31) / 32, FC2C / 128, BATCH), 256, 0, stream>>>(y1, Wfc2, Wlast, out);
}

// Round 3
// 7534.010 us; speedup vs baseline: 1.4485x; 1.4485x over previous
//
#include <hip/hip_runtime.h>
#include <hip/hip_bf16.h>

#define BATCH 4
#define TLEN 16384
#define CH 128
#define HC 64
#define TPRIME 10246
#define LDIFF 3069
#define NLAYERS 30
#define FC1C 2048
#define FC2C 256
#define CHUNK 5123           // TPRIME/2
#define NR 5125              // CHUNK + 2 halo rows

typedef short bf16x8 __attribute__((ext_vector_type(8)));
typedef float f32x4 __attribute__((ext_vector_type(4)));
#define MFMA(a, b, c) __builtin_amdgcn_mfma_f32_16x16x32_bf16(a, b, c, 0, 0, 0)

static __device__ __forceinline__ short f2b(float f) {
    __hip_bfloat16 h = __float2bfloat16(f);
    return *reinterpret_cast<short*>(&h);
}

// ---------------------------------------------------------------- first conv (r1, proven)
__global__ __launch_bounds__(256) void k_first(const float* __restrict__ x,
                                               const float* __restrict__ Wf,
                                               float* __restrict__ h) {
    int b = blockIdx.y;
    int t = blockIdx.x * 256 + threadIdx.x;
    const float* xb = x + (size_t)b * TLEN;
    float xm = (t > 0) ? xb[t - 1] : 0.f;
    float x0 = xb[t];
    float xp = (t < TLEN - 1) ? xb[t + 1] : 0.f;
    float* hb = h + (size_t)b * CH * TLEN;
#pragma unroll 4
    for (int co = 0; co < CH; ++co) {
        float w0 = Wf[co * 3], w1 = Wf[co * 3 + 1], w2 = Wf[co * 3 + 2];
        hb[(size_t)co * TLEN + t] = w0 * xm + w1 * x0 + w2 * xp;
    }
}

// ------------------------------------------- transpose skip/res 1x1 weights (r1, proven)
__global__ void k_prep(const float* __restrict__ Ws, const float* __restrict__ Wr,
                       float* __restrict__ WsT, float* __restrict__ WrT) {
    int idx = blockIdx.x * 256 + threadIdx.x;  // over NLAYERS*CH*HC
    if (idx >= NLAYERS * CH * HC) return;
    int l = idx / (CH * HC);
    int r = idx % (CH * HC);
    int co = r / HC, cz = r % HC;
    WsT[((size_t)l * HC + cz) * CH + co] = Ws[idx];
    WrT[((size_t)l * HC + cz) * CH + co] = Wr[idx];
}

// ---------------------------------------------------------------- layer kernel (r1, proven)
__global__ __launch_bounds__(256) void k_layer(
    const float* __restrict__ h_in, float* __restrict__ h_out,
    float* __restrict__ skips,
    const float* __restrict__ Wd,    // [128][128][3] this layer
    const float* __restrict__ WsT,   // [64][128] this layer (transposed)
    const float* __restrict__ WrT,   // [64][128]
    int d) {
    __shared__ __align__(16) float smem[12288];  // 48 KB
    const int tid = threadIdx.x;
    const int b = blockIdx.y;
    const int t0 = blockIdx.x * 32;
    const int lm = tid & 31;   // co group (32)
    const int lh = tid >> 5;   // t group (8)
    const int co0 = lm * 4;
    const int tl0 = lh * 4;
    const float* hb = h_in + (size_t)b * CH * TLEN;

    float acc[4][4] = {};
    float(*WldsT)[132] = (float(*)[132])smem;               // 48 x 132 = 6336
    float(*hs)[16][32] = (float(*)[16][32])(smem + 6336);   // 3 x 16 x 32

#pragma unroll 1
    for (int ci0 = 0; ci0 < CH; ci0 += 16) {
        __syncthreads();
        for (int idx = tid; idx < 128 * 48; idx += 256) {
            int co = idx / 48, j = idx % 48;
            WldsT[j][co] = Wd[co * (CH * 3) + ci0 * 3 + j];
        }
        for (int idx = tid; idx < 3 * 16 * 32; idx += 256) {
            int k = idx >> 9;
            int r = idx & 511;
            int ci = r >> 5, tt = r & 31;
            int tg = t0 + tt + (k - 1) * d;
            float v = 0.f;
            if ((unsigned)tg < TLEN) v = hb[(size_t)(ci0 + ci) * TLEN + tg];
            hs[k][ci][tt] = v;
        }
        __syncthreads();
#pragma unroll
        for (int j = 0; j < 48; ++j) {
            const int ci = j / 3, k = j - 3 * ci;
            const float4 a4 = *(const float4*)&WldsT[j][co0];
            const float4 b4 = *(const float4*)&hs[k][ci][tl0];
            const float av[4] = {a4.x, a4.y, a4.z, a4.w};
            const float bv[4] = {b4.x, b4.y, b4.z, b4.w};
#pragma unroll
            for (int i = 0; i < 4; ++i)
#pragma unroll
                for (int jj = 0; jj < 4; ++jj) acc[i][jj] += av[i] * bv[jj];
        }
    }

    // ---- epilogue: g -> LDS, GLU, skip/res GEMMs (K=64)
    __syncthreads();
    float(*gbuf)[36] = (float(*)[36])smem;                // 128 x 36 = 4608
    float(*zbuf)[36] = (float(*)[36])(smem + 4608);       // 64 x 36 = 2304
    float(*w2s)[132] = (float(*)[132])(smem + 6912);      // 16 x 132 = 2112
    float(*w2r)[132] = (float(*)[132])(smem + 9024);      // 16 x 132
#pragma unroll
    for (int i = 0; i < 4; ++i) {
        float4 v = make_float4(acc[i][0], acc[i][1], acc[i][2], acc[i][3]);
        *(float4*)&gbuf[co0 + i][tl0] = v;
    }
    __syncthreads();
#pragma unroll
    for (int r = 0; r < 8; ++r) {
        int id = r * 256 + tid;  // lanes contiguous in t
        int c = id >> 5, tt = id & 31;
        float a = gbuf[c][tt];
        float g2 = gbuf[c + 64][tt];
        float th = tanhf(a);
        float sg = 1.f / (1.f + __expf(-g2));
        zbuf[c][tt] = th * sg;
    }
    float accS[4][4] = {}, accR[4][4] = {};
#pragma unroll 1
    for (int czc = 0; czc < HC; czc += 16) {
        __syncthreads();
        for (int idx = tid; idx < 16 * 128; idx += 256) {
            int cz = idx >> 7, co = idx & 127;
            w2s[cz][co] = WsT[(size_t)(czc + cz) * CH + co];
            w2r[cz][co] = WrT[(size_t)(czc + cz) * CH + co];
        }
        __syncthreads();
#pragma unroll
        for (int cz = 0; cz < 16; ++cz) {
            const float4 z4 = *(const float4*)&zbuf[czc + cz][tl0];
            const float4 s4 = *(const float4*)&w2s[cz][co0];
            const float4 r4 = *(const float4*)&w2r[cz][co0];
            const float zv[4] = {z4.x, z4.y, z4.z, z4.w};
            const float sv[4] = {s4.x, s4.y, s4.z, s4.w};
            const float rv[4] = {r4.x, r4.y, r4.z, r4.w};
#pragma unroll
            for (int i = 0; i < 4; ++i)
#pragma unroll
                for (int jj = 0; jj < 4; ++jj) {
                    accS[i][jj] += sv[i] * zv[jj];
                    accR[i][jj] += rv[i] * zv[jj];
                }
        }
    }
    const float scale = 0.70710678118654752f;
    float* hob = h_out + (size_t)b * CH * TLEN;
#pragma unroll
    for (int i = 0; i < 4; ++i) {
        int co = co0 + i;
        const float4 hi = *(const float4*)&hb[(size_t)co * TLEN + t0 + tl0];
        float4 ho;
        ho.x = (hi.x + accR[i][0]) * scale;
        ho.y = (hi.y + accR[i][1]) * scale;
        ho.z = (hi.z + accR[i][2]) * scale;
        ho.w = (hi.w + accR[i][3]) * scale;
        *(float4*)&hob[(size_t)co * TLEN + t0 + tl0] = ho;
#pragma unroll
        for (int jj = 0; jj < 4; ++jj) {
            int ts = t0 + tl0 + jj - LDIFF;
            if ((unsigned)ts < TPRIME)
                skips[((size_t)b * CH + co) * TPRIME + ts] += accS[i][jj];
        }
    }
}

// ---------------------------------------------------------------- MFMA weight packer
// out layout: [cob][tap][kc][kg(4)][co(128)][j(8)]  (bf16), ci = kc*32+kg*8+j
__global__ void k_prep_conv(const float* __restrict__ W, short* __restrict__ Wp,
                            int CIN, int KC, int total) {
    int o = blockIdx.x * 256 + threadIdx.x;
    if (o >= total) return;
    int j = o & 7;
    int co = (o >> 3) & 127;
    int kg = (o >> 10) & 3;
    int rest = o >> 12;       // = (cob*3+tap)*KC + kc
    int kc = rest % KC;
    int ct = rest / KC;
    int tap = ct % 3;
    int cob = ct / 3;
    int ci = kc * 32 + kg * 8 + j;
    int cog = cob * 128 + co;
    Wp[o] = f2b(W[((size_t)cog * CIN + ci) * 3 + tap]);
}

// ---------------------------- skips [b][c][t'] fp32 -> relu -> bf16 [b][t'][c]
__global__ __launch_bounds__(256) void k_skipT(const float* __restrict__ sk,
                                               short* __restrict__ sbf) {
    int gid = blockIdx.x * 256 + threadIdx.x;   // B*TPRIME*32 units of 4 ch
    int c4 = (gid & 31) * 4;
    int rest = gid >> 5;
    int t = rest % TPRIME;
    int b = rest / TPRIME;
    const float* sb = sk + (size_t)b * CH * TPRIME;
    short4 o;
    o.x = f2b(fmaxf(sb[(size_t)(c4 + 0) * TPRIME + t], 0.f));
    o.y = f2b(fmaxf(sb[(size_t)(c4 + 1) * TPRIME + t], 0.f));
    o.z = f2b(fmaxf(sb[(size_t)(c4 + 2) * TPRIME + t], 0.f));
    o.w = f2b(fmaxf(sb[(size_t)(c4 + 3) * TPRIME + t], 0.f));
    *(short4*)(sbf + ((size_t)b * TPRIME + t) * CH + c4) = o;
}

// ---------------------------------------------------------------- fc1 (MFMA)
__global__ __launch_bounds__(256) void k_fc1(const short* __restrict__ sbf,
                                             const short* __restrict__ Wp,  // [16][3][4][4][128][8]
                                             short* __restrict__ y1, int c0) {
    __shared__ __align__(16) short smem[8192];
    const int tid = threadIdx.x;
    const int l = tid & 63;
    const int w = tid >> 6;
    const int b = blockIdx.z;
    const int cob = blockIdx.y;
    const int row0 = blockIdx.x * 128;
    const int coq = (w & 1) * 64;
    const int tq = (w >> 1) * 64;
    const int lm = l & 15;
    const int quad = l >> 4;
    const short* sb = sbf + (size_t)b * TPRIME * CH;
    f32x4 acc[4][4] = {};
    for (int tap = 0; tap < 3; ++tap) {
        const int toff = tap - 1;
        for (int kc = 0; kc < 4; ++kc) {
            __syncthreads();
            const int4* Ag = (const int4*)(Wp + (((size_t)cob * 3 + tap) * 4 + kc) * 4096);
            ((int4*)smem)[tid] = Ag[tid];
            ((int4*)smem)[tid + 256] = Ag[tid + 256];
            int4* Bl = (int4*)(smem + 4096);
            for (int u = tid; u < 512; u += 256) {
                int kg = u >> 7, tt = u & 127;
                int tg = c0 - 1 + row0 + tt + toff;
                int4 v = make_int4(0, 0, 0, 0);
                if ((unsigned)tg < TPRIME)
                    v = *(const int4*)(sb + (size_t)tg * CH + kc * 32 + kg * 8);
                Bl[u] = v;
            }
            __syncthreads();
            bf16x8 af[4], bfr[4];
#pragma unroll
            for (int i = 0; i < 4; ++i)
                af[i] = *(const bf16x8*)(smem + (quad * 128 + coq + i * 16 + lm) * 8);
#pragma unroll
            for (int j = 0; j < 4; ++j)
                bfr[j] = *(const bf16x8*)(smem + 4096 + (quad * 128 + tq + j * 16 + lm) * 8);
#pragma unroll
            for (int i = 0; i < 4; ++i)
#pragma unroll
                for (int j = 0; j < 4; ++j)
                    acc[i][j] = MFMA(af[i], bfr[j], acc[i][j]);
        }
    }
    short* yb = y1 + (size_t)b * NR * FC1C + cob * 128;
#pragma unroll
    for (int i = 0; i < 4; ++i)
#pragma unroll
        for (int j = 0; j < 4; ++j) {
            int row = row0 + tq + j * 16 + lm;
            int tg = c0 - 1 + row;
            int co = coq + i * 16 + quad * 4;
            if (row < NR && (unsigned)tg < TPRIME) {
                short4 v;
                v.x = f2b(fmaxf(acc[i][j][0], 0.f));
                v.y = f2b(fmaxf(acc[i][j][1], 0.f));
                v.z = f2b(fmaxf(acc[i][j][2], 0.f));
                v.w = f2b(fmaxf(acc[i][j][3], 0.f));
                *(short4*)(yb + (size_t)row * FC1C + co) = v;
            }
        }
}

// ---------------------------------------------------------------- fc2 (MFMA) + fused 1x1 head
__global__ __launch_bounds__(256) void k_fc2(const short* __restrict__ y1,
                                             const short* __restrict__ Wp,  // [2][3][64][4][128][8]
                                             const float* __restrict__ Wlast,
                                             float* __restrict__ out, int c0) {
    __shared__ __align__(16) short smem[8192];
    __shared__ float red[128];
    const int tid = threadIdx.x;
    const int l = tid & 63;
    const int w = tid >> 6;
    const int b = blockIdx.z;
    const int cob = blockIdx.y;
    const int t0 = c0 + blockIdx.x * 128;
    const int coq = (w & 1) * 64;
    const int tq = (w >> 1) * 64;
    const int lm = l & 15;
    const int quad = l >> 4;
    const short* yb = y1 + (size_t)b * NR * FC1C;
    f32x4 acc[4][4] = {};
    for (int tap = 0; tap < 3; ++tap) {
        const int toff = tap - 1;
        for (int kc = 0; kc < 64; ++kc) {
            __syncthreads();
            const int4* Ag = (const int4*)(Wp + (((size_t)cob * 3 + tap) * 64 + kc) * 4096);
            ((int4*)smem)[tid] = Ag[tid];
            ((int4*)smem)[tid + 256] = Ag[tid + 256];
            int4* Bl = (int4*)(smem + 4096);
            for (int u = tid; u < 512; u += 256) {
                int kg = u >> 7, tt = u & 127;
                int tg = t0 + tt + toff;
                int row = tg - (c0 - 1);
                int4 v = make_int4(0, 0, 0, 0);
                if ((unsigned)tg < TPRIME && (unsigned)row < NR)
                    v = *(const int4*)(yb + (size_t)row * FC1C + kc * 32 + kg * 8);
                Bl[u] = v;
            }
            __syncthreads();
            bf16x8 af[4], bfr[4];
#pragma unroll
            for (int i = 0; i < 4; ++i)
                af[i] = *(const bf16x8*)(smem + (quad * 128 + coq + i * 16 + lm) * 8);
#pragma unroll
            for (int j = 0; j < 4; ++j)
                bfr[j] = *(const bf16x8*)(smem + 4096 + (quad * 128 + tq + j * 16 + lm) * 8);
#pragma unroll
            for (int i = 0; i < 4; ++i)
#pragma unroll
                for (int j = 0; j < 4; ++j)
                    acc[i][j] = MFMA(af[i], bfr[j], acc[i][j]);
        }
    }
    for (int r = tid; r < 128; r += 256) red[r] = 0.f;
    __syncthreads();
    float4 wv[4];
#pragma unroll
    for (int i = 0; i < 4; ++i)
        wv[i] = *(const float4*)(Wlast + cob * 128 + coq + i * 16 + quad * 4);
#pragma unroll
    for (int j = 0; j < 4; ++j) {
        float s = 0.f;
#pragma unroll
        for (int i = 0; i < 4; ++i)
            s += wv[i].x * acc[i][j][0] + wv[i].y * acc[i][j][1] +
                 wv[i].z * acc[i][j][2] + wv[i].w * acc[i][j][3];
        atomicAdd(&red[tq + j * 16 + lm], s);
    }
    __syncthreads();
    if (tid < 128) {
        int tg = t0 + tid;
        if (tg < c0 + CHUNK) atomicAdd(&out[(size_t)b * TPRIME + tg], red[tid]);
    }
}

// ---------------------------------------------------------------- bias init
__global__ void k_bias(float* __restrict__ out, const float* __restrict__ bl) {
    int i = blockIdx.x * 256 + threadIdx.x;
    if (i < BATCH * TPRIME) out[i] = bl[0];
}

extern "C" void kernel_launch(void* const* d_in, const int* in_sizes, int n_in,
                              void* d_out, int out_size, void* d_ws, size_t ws_size,
                              hipStream_t stream) {
    const float* x = (const float*)d_in[0];
    const float* Wf = (const float*)d_in[1];
    const float* Wdil = (const float*)d_in[2];
    const float* Wskip = (const float*)d_in[3];
    const float* Wres = (const float*)d_in[4];
    const float* Wfc1 = (const float*)d_in[5];
    const float* Wfc2 = (const float*)d_in[6];
    const float* Wlast = (const float*)d_in[7];
    const float* blast = (const float*)d_in[8];
    float* out = (float*)d_out;

    char* p = (char*)d_ws;
    auto alloc = [&](size_t bytes) { char* r = p; p += (bytes + 255) & ~(size_t)255; return r; };
    float* skips = (float*)alloc((size_t)BATCH * CH * TPRIME * 4);       // 21 MB, [b][c][t']
    float* WsT   = (float*)alloc((size_t)NLAYERS * HC * CH * 4);
    float* WrT   = (float*)alloc((size_t)NLAYERS * HC * CH * 4);
    short* Wp1   = (short*)alloc((size_t)786432 * 2);
    short* Wp2   = (short*)alloc((size_t)1572864 * 2);
    char*  big   = alloc((size_t)94459904);                              // 94.5 MB shared region
    float* hA = (float*)big;                                   // layers phase (33.55 MB)
    float* hB = (float*)(big + (size_t)BATCH * CH * TLEN * 4); // layers phase (33.55 MB)
    short* sbf = (short*)big;                                  // head phase (10.5 MB)
    short* y1  = (short*)(big + (size_t)BATCH * TPRIME * CH * 2);  // head phase (84 MB)

    k_prep<<<(NLAYERS * CH * HC + 255) / 256, 256, 0, stream>>>(Wskip, Wres, WsT, WrT);
    k_prep_conv<<<786432 / 256, 256, 0, stream>>>(Wfc1, Wp1, 128, 4, 786432);
    k_prep_conv<<<1572864 / 256, 256, 0, stream>>>(Wfc2, Wp2, 2048, 64, 1572864);
    hipMemsetAsync(skips, 0, (size_t)BATCH * CH * TPRIME * 4, stream);
    k_first<<<dim3(TLEN / 256, BATCH), 256, 0, stream>>>(x, Wf, hA);

    float* hin = hA;
    float* hout = hB;
    for (int l = 0; l < NLAYERS; ++l) {
        int d = 1 << (l % 10);
        k_layer<<<dim3(TLEN / 32, BATCH), 256, 0, stream>>>(
            hin, hout, skips, Wdil + (size_t)l * CH * CH * 3,
            WsT + (size_t)l * HC * CH, WrT + (size_t)l * HC * CH, d);
        float* tmp = hin; hin = hout; hout = tmp;
    }

    // h buffers dead from here; big region becomes sbf + y1
    k_skipT<<<(BATCH * TPRIME * 32) / 256, 256, 0, stream>>>(skips, sbf);
    k_bias<<<(BATCH * TPRIME + 255) / 256, 256, 0, stream>>>(out, blast);
    for (int c = 0; c < 2; ++c) {
        int c0 = c * CHUNK;
        k_fc1<<<dim3(41, FC1C / 128, BATCH), 256, 0, stream>>>(sbf, Wp1, y1, c0);
        k_fc2<<<dim3(41, FC2C / 128, BATCH), 256, 0, stream>>>(y1, Wp2, Wlast, out, c0);
    }
}

// Round 4
// 2188.928 us; speedup vs baseline: 4.9856x; 3.4419x over previous
//
#include <hip/hip_runtime.h>
#include <hip/hip_bf16.h>

#define BATCH 4
#define TLEN 16384
#define CH 128
#define HC 64
#define TPRIME 10246
#define LDIFF 3069
#define NLAYERS 30
#define FC1C 2048
#define FC2C 256
#define CHUNK 2562           // ceil(TPRIME/4)
#define NR 2564              // CHUNK + 2 halo rows
#define NCHUNK 4

typedef short bf16x8 __attribute__((ext_vector_type(8)));
typedef float f32x4 __attribute__((ext_vector_type(4)));
#define MFMA(a, b, c) __builtin_amdgcn_mfma_f32_16x16x32_bf16(a, b, c, 0, 0, 0)

static __device__ __forceinline__ short f2b(float f) {
    __hip_bfloat16 h = __float2bfloat16(f);
    return *reinterpret_cast<short*>(&h);
}
static __device__ __forceinline__ float b2f(short s) {
    __hip_bfloat16 h;
    *reinterpret_cast<short*>(&h) = s;
    return __bfloat162float(h);
}

// ---------------------------------------------------------------- MFMA weight packer (PROVEN r3)
// out layout: [cob][tap][kc][kg(4)][co(128)][j(8)]  (bf16), ci = kc*32+kg*8+j
__global__ void k_prep_conv(const float* __restrict__ W, short* __restrict__ Wp,
                            int CIN, int KC, int total) {
    int o = blockIdx.x * 256 + threadIdx.x;
    if (o >= total) return;
    int j = o & 7;
    int co = (o >> 3) & 127;
    int kg = (o >> 10) & 3;
    int rest = o >> 12;       // = (cob*3+tap)*KC + kc
    int kc = rest % KC;
    int ct = rest / KC;
    int tap = ct % 3;
    int cob = ct / 3;
    int ci = kc * 32 + kg * 8 + j;
    int cog = cob * 128 + co;
    Wp[o] = f2b(W[((size_t)cog * CIN + ci) * 3 + tap]);
}

// skip/res 1x1 weights: out [layer][kg(8)][co(128)][j(8)], cz = kg*8+j
__global__ void k_prep_sr(const float* __restrict__ Ws, const float* __restrict__ Wr,
                          short* __restrict__ Wsp, short* __restrict__ Wrp) {
    int o = blockIdx.x * 256 + threadIdx.x;
    if (o >= NLAYERS * 8192) return;
    int j = o & 7;
    int co = (o >> 3) & 127;
    int kg = (o >> 10) & 7;
    int lay = o >> 13;
    size_t in = ((size_t)lay * 128 + co) * 64 + kg * 8 + j;
    Wsp[o] = f2b(Ws[in]);
    Wrp[o] = f2b(Wr[in]);
}

// ---------------------------------------------------------------- first conv -> h[b][t][c] bf16
__global__ __launch_bounds__(256) void k_first(const float* __restrict__ x,
                                               const float* __restrict__ Wf,
                                               short* __restrict__ h) {
    int gid = blockIdx.x * 256 + threadIdx.x;   // B*T*32 units of 4 co
    int co4 = (gid & 31) * 4;
    int t = (gid >> 5) & (TLEN - 1);
    int b = gid >> 19;
    const float* xb = x + (size_t)b * TLEN;
    float xm = t > 0 ? xb[t - 1] : 0.f;
    float x0 = xb[t];
    float xp = t < TLEN - 1 ? xb[t + 1] : 0.f;
    short4 o;
    float r[4];
#pragma unroll
    for (int i = 0; i < 4; ++i) {
        const float* wp = Wf + (co4 + i) * 3;
        r[i] = wp[0] * xm + wp[1] * x0 + wp[2] * xp;
    }
    o.x = f2b(r[0]); o.y = f2b(r[1]); o.z = f2b(r[2]); o.w = f2b(r[3]);
    *(short4*)(h + (size_t)b * TLEN * CH + (size_t)t * CH + co4) = o;
}

// ---------------------------------------------------------------- layer: conv->GLU->skip/res (MFMA)
// Wave mapping: wave w owns co[0..128) x t[w*32..w*32+32). GLU pairs (co, co+64)
// live in the same lane (acc[i] filter, acc[i+4] gate) -> fp32 in-register GLU.
__global__ __launch_bounds__(256) void k_layer(
    const short* __restrict__ hin, short* __restrict__ hout,
    float* __restrict__ skips,              // [b][t'][c] fp32 accum
    const short* __restrict__ Wp,           // [3][4][4][128][8] this layer
    const short* __restrict__ Wsp,          // [8][128][8] this layer
    const short* __restrict__ Wrp,
    int d) {
    __shared__ __align__(16) short smem[32768];  // 64 KB
    short* SA = smem;            // conv A tile   [0,4096)
    short* SB = smem + 4096;     // conv B tile   [4096,8192)
    short* SZ = smem + 8192;     // z  [kg8][tt128][j8]  [8192,16384)
    short* SW = smem + 16384;    // Ws [kg8][co128][j8]  [16384,24576)
    short* SR = smem + 24576;    // Wr                   [24576,32768)
    const int tid = threadIdx.x;
    const int l = tid & 63;
    const int w = tid >> 6;
    const int lm = l & 15;
    const int quad = l >> 4;
    const int b = blockIdx.y;
    const int t0 = blockIdx.x * 128;
    const int tq = w * 32;
    const short* hb = hin + (size_t)b * TLEN * CH;

    // stage skip/res weights for epilogue: FULL 1024 int4 each (r2 bug: was 512)
    {
        int4* dw = (int4*)SW; const int4* sw = (const int4*)Wsp;
        int4* dr = (int4*)SR; const int4* sr = (const int4*)Wrp;
        for (int u = tid; u < 1024; u += 256) { dw[u] = sw[u]; dr[u] = sr[u]; }
    }

    f32x4 acc[8][2] = {};
    for (int tap = 0; tap < 3; ++tap) {
        const int toff = (tap - 1) * d;
        for (int kc = 0; kc < 4; ++kc) {
            __syncthreads();
            const int4* Ag = (const int4*)(Wp + (tap * 4 + kc) * 4096);
            int4* Al = (int4*)SA;
            Al[tid] = Ag[tid];
            Al[tid + 256] = Ag[tid + 256];
            int4* Bl = (int4*)SB;
#pragma unroll
            for (int u = tid; u < 512; u += 256) {
                int kg = u >> 7, tt = u & 127;
                int tg = t0 + tt + toff;
                int4 v = make_int4(0, 0, 0, 0);
                if ((unsigned)tg < TLEN)
                    v = *(const int4*)(hb + (size_t)tg * CH + kc * 32 + kg * 8);
                Bl[u] = v;
            }
            __syncthreads();
            bf16x8 af[8], bfr[2];
#pragma unroll
            for (int i = 0; i < 8; ++i)
                af[i] = *(const bf16x8*)(SA + (quad * 128 + i * 16 + lm) * 8);
#pragma unroll
            for (int j = 0; j < 2; ++j)
                bfr[j] = *(const bf16x8*)(SB + (quad * 128 + tq + j * 16 + lm) * 8);
#pragma unroll
            for (int i = 0; i < 8; ++i)
#pragma unroll
                for (int j = 0; j < 2; ++j)
                    acc[i][j] = MFMA(af[i], bfr[j], acc[i][j]);
        }
    }

    // ---- GLU in-register (fp32), write z to LDS in B-operand layout
#pragma unroll
    for (int i = 0; i < 4; ++i)
#pragma unroll
        for (int j = 0; j < 2; ++j) {
            short zo[4];
#pragma unroll
            for (int r = 0; r < 4; ++r) {
                float a = acc[i][j][r];        // co = i*16+quad*4+r  (filter)
                float g = acc[i + 4][j][r];    // co + 64             (gate)
                float th = tanhf(a);
                float sg = 1.f / (1.f + __expf(-g));
                zo[r] = f2b(th * sg);
            }
            int co = i * 16 + quad * 4;        // cz in [0,64)
            int kg = co >> 3;
            int jj0 = co & 7;                  // 0 or 4
            short4 zv = {zo[0], zo[1], zo[2], zo[3]};
            *(short4*)(SZ + (kg * 128 + tq + j * 16 + lm) * 8 + jj0) = zv;
        }
    __syncthreads();

    // ---- skip/res GEMMs, K=64
    f32x4 aS[8][2] = {}, aR[8][2] = {};
#pragma unroll
    for (int kk = 0; kk < 2; ++kk) {
        int kgg = kk * 4 + quad;
        bf16x8 zs[2], wsf[8], wrf[8];
#pragma unroll
        for (int j = 0; j < 2; ++j)
            zs[j] = *(const bf16x8*)(SZ + (kgg * 128 + tq + j * 16 + lm) * 8);
#pragma unroll
        for (int i = 0; i < 8; ++i) {
            wsf[i] = *(const bf16x8*)(SW + (kgg * 128 + i * 16 + lm) * 8);
            wrf[i] = *(const bf16x8*)(SR + (kgg * 128 + i * 16 + lm) * 8);
        }
#pragma unroll
        for (int i = 0; i < 8; ++i)
#pragma unroll
            for (int j = 0; j < 2; ++j) {
                aS[i][j] = MFMA(wsf[i], zs[j], aS[i][j]);
                aR[i][j] = MFMA(wrf[i], zs[j], aR[i][j]);
            }
    }

    const float scale = 0.70710678118654752f;
    short* hob = hout + (size_t)b * TLEN * CH;
    float* skb = skips + (size_t)b * TPRIME * CH;
#pragma unroll
    for (int i = 0; i < 8; ++i)
#pragma unroll
        for (int j = 0; j < 2; ++j) {
            int tt = tq + j * 16 + lm;
            int tg = t0 + tt;
            int co = i * 16 + quad * 4;
            short4 hv = *(const short4*)(hb + (size_t)tg * CH + co);
            short4 ho;
            ho.x = f2b((b2f(hv.x) + aR[i][j][0]) * scale);
            ho.y = f2b((b2f(hv.y) + aR[i][j][1]) * scale);
            ho.z = f2b((b2f(hv.z) + aR[i][j][2]) * scale);
            ho.w = f2b((b2f(hv.w) + aR[i][j][3]) * scale);
            *(short4*)(hob + (size_t)tg * CH + co) = ho;
            int ts = tg - LDIFF;
            if ((unsigned)ts < TPRIME) {
                float4* sp = (float4*)(skb + (size_t)ts * CH + co);
                float4 sv = *sp;
                sv.x += aS[i][j][0]; sv.y += aS[i][j][1];
                sv.z += aS[i][j][2]; sv.w += aS[i][j][3];
                *sp = sv;
            }
        }
}

// ---------------------------- skips fp32 [b][t'][c] -> relu -> bf16 (elementwise)
__global__ __launch_bounds__(256) void k_skipcvt(const float* __restrict__ sk,
                                                 short* __restrict__ sbf) {
    int gid = blockIdx.x * 256 + threadIdx.x;
    size_t base = (size_t)gid * 4;
    float4 v = *(const float4*)(sk + base);
    short4 o;
    o.x = f2b(fmaxf(v.x, 0.f)); o.y = f2b(fmaxf(v.y, 0.f));
    o.z = f2b(fmaxf(v.z, 0.f)); o.w = f2b(fmaxf(v.w, 0.f));
    *(short4*)(sbf + base) = o;
}

// ---------------------------------------------------------------- fc1 (MFMA, PROVEN r3)
__global__ __launch_bounds__(256) void k_fc1(const short* __restrict__ sbf,
                                             const short* __restrict__ Wp,  // [16][3][4][4][128][8]
                                             short* __restrict__ y1, int c0) {
    __shared__ __align__(16) short smem[8192];
    const int tid = threadIdx.x;
    const int l = tid & 63;
    const int w = tid >> 6;
    const int b = blockIdx.z;
    const int cob = blockIdx.y;
    const int row0 = blockIdx.x * 128;
    const int coq = (w & 1) * 64;
    const int tq = (w >> 1) * 64;
    const int lm = l & 15;
    const int quad = l >> 4;
    const short* sb = sbf + (size_t)b * TPRIME * CH;
    f32x4 acc[4][4] = {};
    for (int tap = 0; tap < 3; ++tap) {
        const int toff = tap - 1;
        for (int kc = 0; kc < 4; ++kc) {
            __syncthreads();
            const int4* Ag = (const int4*)(Wp + (((size_t)cob * 3 + tap) * 4 + kc) * 4096);
            ((int4*)smem)[tid] = Ag[tid];
            ((int4*)smem)[tid + 256] = Ag[tid + 256];
            int4* Bl = (int4*)(smem + 4096);
            for (int u = tid; u < 512; u += 256) {
                int kg = u >> 7, tt = u & 127;
                int tg = c0 - 1 + row0 + tt + toff;
                int4 v = make_int4(0, 0, 0, 0);
                if ((unsigned)tg < TPRIME)
                    v = *(const int4*)(sb + (size_t)tg * CH + kc * 32 + kg * 8);
                Bl[u] = v;
            }
            __syncthreads();
            bf16x8 af[4], bfr[4];
#pragma unroll
            for (int i = 0; i < 4; ++i)
                af[i] = *(const bf16x8*)(smem + (quad * 128 + coq + i * 16 + lm) * 8);
#pragma unroll
            for (int j = 0; j < 4; ++j)
                bfr[j] = *(const bf16x8*)(smem + 4096 + (quad * 128 + tq + j * 16 + lm) * 8);
#pragma unroll
            for (int i = 0; i < 4; ++i)
#pragma unroll
                for (int j = 0; j < 4; ++j)
                    acc[i][j] = MFMA(af[i], bfr[j], acc[i][j]);
        }
    }
    short* yb = y1 + (size_t)b * NR * FC1C + cob * 128;
#pragma unroll
    for (int i = 0; i < 4; ++i)
#pragma unroll
        for (int j = 0; j < 4; ++j) {
            int row = row0 + tq + j * 16 + lm;
            int tg = c0 - 1 + row;
            int co = coq + i * 16 + quad * 4;
            if (row < NR && (unsigned)tg < TPRIME) {
                short4 v;
                v.x = f2b(fmaxf(acc[i][j][0], 0.f));
                v.y = f2b(fmaxf(acc[i][j][1], 0.f));
                v.z = f2b(fmaxf(acc[i][j][2], 0.f));
                v.w = f2b(fmaxf(acc[i][j][3], 0.f));
                *(short4*)(yb + (size_t)row * FC1C + co) = v;
            }
        }
}

// ---------------------------------------------------------------- fc2 (MFMA, PROVEN r3) + 1x1 head
__global__ __launch_bounds__(256) void k_fc2(const short* __restrict__ y1,
                                             const short* __restrict__ Wp,  // [2][3][64][4][128][8]
                                             const float* __restrict__ Wlast,
                                             float* __restrict__ out, int c0) {
    __shared__ __align__(16) short smem[8192];
    __shared__ float red[128];
    const int tid = threadIdx.x;
    const int l = tid & 63;
    const int w = tid >> 6;
    const int b = blockIdx.z;
    const int cob = blockIdx.y;
    const int t0 = c0 + blockIdx.x * 128;
    const int coq = (w & 1) * 64;
    const int tq = (w >> 1) * 64;
    const int lm = l & 15;
    const int quad = l >> 4;
    const short* yb = y1 + (size_t)b * NR * FC1C;
    f32x4 acc[4][4] = {};
    for (int tap = 0; tap < 3; ++tap) {
        const int toff = tap - 1;
        for (int kc = 0; kc < 64; ++kc) {
            __syncthreads();
            const int4* Ag = (const int4*)(Wp + (((size_t)cob * 3 + tap) * 64 + kc) * 4096);
            ((int4*)smem)[tid] = Ag[tid];
            ((int4*)smem)[tid + 256] = Ag[tid + 256];
            int4* Bl = (int4*)(smem + 4096);
            for (int u = tid; u < 512; u += 256) {
                int kg = u >> 7, tt = u & 127;
                int tg = t0 + tt + toff;
                int row = tg - (c0 - 1);
                int4 v = make_int4(0, 0, 0, 0);
                if ((unsigned)tg < TPRIME && (unsigned)row < NR)
                    v = *(const int4*)(yb + (size_t)row * FC1C + kc * 32 + kg * 8);
                Bl[u] = v;
            }
            __syncthreads();
            bf16x8 af[4], bfr[4];
#pragma unroll
            for (int i = 0; i < 4; ++i)
                af[i] = *(const bf16x8*)(smem + (quad * 128 + coq + i * 16 + lm) * 8);
#pragma unroll
            for (int j = 0; j < 4; ++j)
                bfr[j] = *(const bf16x8*)(smem + 4096 + (quad * 128 + tq + j * 16 + lm) * 8);
#pragma unroll
            for (int i = 0; i < 4; ++i)
#pragma unroll
                for (int j = 0; j < 4; ++j)
                    acc[i][j] = MFMA(af[i], bfr[j], acc[i][j]);
        }
    }
    for (int r = tid; r < 128; r += 256) red[r] = 0.f;
    __syncthreads();
    float4 wv[4];
#pragma unroll
    for (int i = 0; i < 4; ++i)
        wv[i] = *(const float4*)(Wlast + cob * 128 + coq + i * 16 + quad * 4);
#pragma unroll
    for (int j = 0; j < 4; ++j) {
        float s = 0.f;
#pragma unroll
        for (int i = 0; i < 4; ++i)
            s += wv[i].x * acc[i][j][0] + wv[i].y * acc[i][j][1] +
                 wv[i].z * acc[i][j][2] + wv[i].w * acc[i][j][3];
        atomicAdd(&red[tq + j * 16 + lm], s);
    }
    __syncthreads();
    if (tid < 128) {
        int tg = t0 + tid;
        if (tg < c0 + CHUNK && tg < TPRIME)
            atomicAdd(&out[(size_t)b * TPRIME + tg], red[tid]);
    }
}

// ---------------------------------------------------------------- bias init
__global__ void k_bias(float* __restrict__ out, const float* __restrict__ bl) {
    int i = blockIdx.x * 256 + threadIdx.x;
    if (i < BATCH * TPRIME) out[i] = bl[0];
}

extern "C" void kernel_launch(void* const* d_in, const int* in_sizes, int n_in,
                              void* d_out, int out_size, void* d_ws, size_t ws_size,
                              hipStream_t stream) {
    const float* x = (const float*)d_in[0];
    const float* Wf = (const float*)d_in[1];
    const float* Wdil = (const float*)d_in[2];
    const float* Wskip = (const float*)d_in[3];
    const float* Wres = (const float*)d_in[4];
    const float* Wfc1 = (const float*)d_in[5];
    const float* Wfc2 = (const float*)d_in[6];
    const float* Wlast = (const float*)d_in[7];
    const float* blast = (const float*)d_in[8];
    float* out = (float*)d_out;

    char* p = (char*)d_ws;
    auto alloc = [&](size_t bytes) { char* r = p; p += (bytes + 255) & ~(size_t)255; return r; };
    float* skips = (float*)alloc((size_t)BATCH * TPRIME * CH * 4);   // 21.0 MB [b][t'][c]
    short* WpD   = (short*)alloc((size_t)NLAYERS * 49152 * 2);       // 2.95 MB
    short* Wsp   = (short*)alloc((size_t)NLAYERS * 8192 * 2);        // 0.49 MB
    short* Wrp   = (short*)alloc((size_t)NLAYERS * 8192 * 2);        // 0.49 MB
    short* Wp1   = (short*)alloc((size_t)786432 * 2);                // 1.5 MB
    short* Wp2   = (short*)alloc((size_t)1572864 * 2);               // 3.0 MB
    char*  big   = alloc((size_t)52500480);                          // 52.5 MB shared region
    short* hA  = (short*)big;                                        // layers: 16.78 MB
    short* hB  = (short*)(big + (size_t)BATCH * TLEN * CH * 2);      // layers: 16.78 MB
    short* sbf = (short*)big;                                        // head: 10.49 MB
    short* y1  = (short*)(big + (size_t)BATCH * TPRIME * CH * 2);    // head: 42.0 MB
    // total ~82.1 MB (proven budget >= 122 MB from r3)

    k_prep_conv<<<5760, 256, 0, stream>>>(Wdil, WpD, 128, 4, 1474560);
    k_prep_conv<<<3072, 256, 0, stream>>>(Wfc1, Wp1, 128, 4, 786432);
    k_prep_conv<<<6144, 256, 0, stream>>>(Wfc2, Wp2, 2048, 64, 1572864);
    k_prep_sr<<<960, 256, 0, stream>>>(Wskip, Wres, Wsp, Wrp);
    hipMemsetAsync(skips, 0, (size_t)BATCH * TPRIME * CH * 4, stream);
    k_first<<<8192, 256, 0, stream>>>(x, Wf, hA);

    short* hin = hA;
    short* hout = hB;
    for (int lyr = 0; lyr < NLAYERS; ++lyr) {
        int d = 1 << (lyr % 10);
        k_layer<<<dim3(TLEN / 128, BATCH), 256, 0, stream>>>(
            hin, hout, skips, WpD + (size_t)lyr * 49152,
            Wsp + (size_t)lyr * 8192, Wrp + (size_t)lyr * 8192, d);
        short* tmp = hin; hin = hout; hout = tmp;
    }

    // h buffers dead; big region becomes sbf + y1
    k_skipcvt<<<5123, 256, 0, stream>>>(skips, sbf);
    k_bias<<<(BATCH * TPRIME + 255) / 256, 256, 0, stream>>>(out, blast);
    for (int c = 0; c < NCHUNK; ++c) {
        int c0 = c * CHUNK;
        k_fc1<<<dim3(21, FC1C / 128, BATCH), 256, 0, stream>>>(sbf, Wp1, y1, c0);
        k_fc2<<<dim3(21, FC2C / 128, BATCH), 256, 0, stream>>>(y1, Wp2, Wlast, out, c0);
    }
}

// Round 5
// 1846.179 us; speedup vs baseline: 5.9112x; 1.1857x over previous
//
#include <hip/hip_runtime.h>
#include <hip/hip_bf16.h>

#define BATCH 4
#define TLEN 16384
#define CH 128
#define HC 64
#define TPRIME 10246
#define LDIFF 3069
#define NLAYERS 30
#define FC1C 2048
#define FC2C 256

typedef short bf16x8 __attribute__((ext_vector_type(8)));
typedef float f32x4 __attribute__((ext_vector_type(4)));
#define MFMA(a, b, c) __builtin_amdgcn_mfma_f32_16x16x32_bf16(a, b, c, 0, 0, 0)

static __device__ __forceinline__ short f2b(float f) {
    __hip_bfloat16 h = __float2bfloat16(f);
    return *reinterpret_cast<short*>(&h);
}
static __device__ __forceinline__ float b2f(short s) {
    __hip_bfloat16 h;
    *reinterpret_cast<short*>(&h) = s;
    return __bfloat162float(h);
}

// ---------------------------------------------------------------- MFMA weight packer (PROVEN r3/r4)
// out layout: [cob][tap][kc][kg(4)][co(128)][j(8)]  (bf16), ci = kc*32+kg*8+j
__global__ void k_prep_conv(const float* __restrict__ W, short* __restrict__ Wp,
                            int CIN, int KC, int total) {
    int o = blockIdx.x * 256 + threadIdx.x;
    if (o >= total) return;
    int j = o & 7;
    int co = (o >> 3) & 127;
    int kg = (o >> 10) & 3;
    int rest = o >> 12;       // = (cob*3+tap)*KC + kc
    int kc = rest % KC;
    int ct = rest / KC;
    int tap = ct % 3;
    int cob = ct / 3;
    int ci = kc * 32 + kg * 8 + j;
    int cog = cob * 128 + co;
    Wp[o] = f2b(W[((size_t)cog * CIN + ci) * 3 + tap]);
}

// skip/res 1x1 weights: out [layer][kg(8)][co(128)][j(8)], cz = kg*8+j (PROVEN r4)
__global__ void k_prep_sr(const float* __restrict__ Ws, const float* __restrict__ Wr,
                          short* __restrict__ Wsp, short* __restrict__ Wrp) {
    int o = blockIdx.x * 256 + threadIdx.x;
    if (o >= NLAYERS * 8192) return;
    int j = o & 7;
    int co = (o >> 3) & 127;
    int kg = (o >> 10) & 7;
    int lay = o >> 13;
    size_t in = ((size_t)lay * 128 + co) * 64 + kg * 8 + j;
    Wsp[o] = f2b(Ws[in]);
    Wrp[o] = f2b(Wr[in]);
}

// ---------------------------------------------------------------- first conv -> h[b][t][c] bf16 (PROVEN r4)
__global__ __launch_bounds__(256) void k_first(const float* __restrict__ x,
                                               const float* __restrict__ Wf,
                                               short* __restrict__ h) {
    int gid = blockIdx.x * 256 + threadIdx.x;   // B*T*32 units of 4 co
    int co4 = (gid & 31) * 4;
    int t = (gid >> 5) & (TLEN - 1);
    int b = gid >> 19;
    const float* xb = x + (size_t)b * TLEN;
    float xm = t > 0 ? xb[t - 1] : 0.f;
    float x0 = xb[t];
    float xp = t < TLEN - 1 ? xb[t + 1] : 0.f;
    short4 o;
    float r[4];
#pragma unroll
    for (int i = 0; i < 4; ++i) {
        const float* wp = Wf + (co4 + i) * 3;
        r[i] = wp[0] * xm + wp[1] * x0 + wp[2] * xp;
    }
    o.x = f2b(r[0]); o.y = f2b(r[1]); o.z = f2b(r[2]); o.w = f2b(r[3]);
    *(short4*)(h + (size_t)b * TLEN * CH + (size_t)t * CH + co4) = o;
}

// ---------------------------------------------------------------- layer kernel (restructured)
// Per-tap full-ci B staging (3 barrier pairs); A + skip/res weights direct from
// global (L2-resident packed images). GLU in-register; z via LDS; skips fp32 RMW.
__global__ __launch_bounds__(256) void k_layer(
    const short* __restrict__ hin, short* __restrict__ hout,
    float* __restrict__ skips,              // [b][t'][c] fp32
    const short* __restrict__ Wp,           // [3][4][4][128][8] this layer
    const short* __restrict__ Wsp,          // [8][128][8] this layer
    const short* __restrict__ Wrp,
    int d) {
    __shared__ __align__(16) short smem[24576];  // 48 KB: SB 32K, SZ 16K
    short* SB = smem;
    short* SZ = smem + 16384;
    const int tid = threadIdx.x;
    const int l = tid & 63;
    const int w = tid >> 6;
    const int lm = l & 15;
    const int quad = l >> 4;
    const int b = blockIdx.y;
    const int t0 = blockIdx.x * 128;
    const int tq = w * 32;
    const short* hb = hin + (size_t)b * TLEN * CH;
    const bf16x8* Wg = (const bf16x8*)Wp;

    f32x4 acc[8][2] = {};
    for (int tap = 0; tap < 3; ++tap) {
        const int toff = (tap - 1) * d;
        __syncthreads();
        int4* Bl = (int4*)SB;
#pragma unroll
        for (int u = tid; u < 2048; u += 256) {
            int kg = u >> 7, tt = u & 127;
            int tg = t0 + tt + toff;
            int4 v = make_int4(0, 0, 0, 0);
            if ((unsigned)tg < TLEN)
                v = *(const int4*)(hb + (size_t)tg * CH + kg * 8);
            Bl[u] = v;
        }
        __syncthreads();
#pragma unroll
        for (int kc = 0; kc < 4; ++kc) {
            bf16x8 af[8], bfr[2];
#pragma unroll
            for (int i = 0; i < 8; ++i)
                af[i] = Wg[(tap * 4 + kc) * 512 + quad * 128 + i * 16 + lm];
#pragma unroll
            for (int j = 0; j < 2; ++j)
                bfr[j] = *(const bf16x8*)(SB + ((kc * 4 + quad) * 128 + tq + j * 16 + lm) * 8);
#pragma unroll
            for (int i = 0; i < 8; ++i)
#pragma unroll
                for (int j = 0; j < 2; ++j)
                    acc[i][j] = MFMA(af[i], bfr[j], acc[i][j]);
        }
    }

    // ---- GLU in-register (fp32), write z to LDS in B-operand layout (PROVEN r4)
#pragma unroll
    for (int i = 0; i < 4; ++i)
#pragma unroll
        for (int j = 0; j < 2; ++j) {
            short zo[4];
#pragma unroll
            for (int r = 0; r < 4; ++r) {
                float a = acc[i][j][r];        // co = i*16+quad*4+r  (filter)
                float g = acc[i + 4][j][r];    // co + 64             (gate)
                float th = tanhf(a);
                float sg = 1.f / (1.f + __expf(-g));
                zo[r] = f2b(th * sg);
            }
            int co = i * 16 + quad * 4;        // cz in [0,64)
            int kg = co >> 3;
            int jj0 = co & 7;                  // 0 or 4
            short4 zv = {zo[0], zo[1], zo[2], zo[3]};
            *(short4*)(SZ + (kg * 128 + tq + j * 16 + lm) * 8 + jj0) = zv;
        }
    __syncthreads();

    // ---- skip/res GEMMs, K=64; weights direct from global (L2)
    const bf16x8* Wsg = (const bf16x8*)Wsp;
    const bf16x8* Wrg = (const bf16x8*)Wrp;
    f32x4 aS[8][2] = {}, aR[8][2] = {};
#pragma unroll
    for (int kk = 0; kk < 2; ++kk) {
        int kgg = kk * 4 + quad;
        bf16x8 zs[2], wsf[8], wrf[8];
#pragma unroll
        for (int j = 0; j < 2; ++j)
            zs[j] = *(const bf16x8*)(SZ + (kgg * 128 + tq + j * 16 + lm) * 8);
#pragma unroll
        for (int i = 0; i < 8; ++i) {
            wsf[i] = Wsg[kgg * 128 + i * 16 + lm];
            wrf[i] = Wrg[kgg * 128 + i * 16 + lm];
        }
#pragma unroll
        for (int i = 0; i < 8; ++i)
#pragma unroll
            for (int j = 0; j < 2; ++j) {
                aS[i][j] = MFMA(wsf[i], zs[j], aS[i][j]);
                aR[i][j] = MFMA(wrf[i], zs[j], aR[i][j]);
            }
    }

    const float scale = 0.70710678118654752f;
    short* hob = hout + (size_t)b * TLEN * CH;
    float* skb = skips + (size_t)b * TPRIME * CH;
    const bool anyskip = (t0 + 127 >= LDIFF) && (t0 < LDIFF + TPRIME);
#pragma unroll
    for (int i = 0; i < 8; ++i)
#pragma unroll
        for (int j = 0; j < 2; ++j) {
            int tt = tq + j * 16 + lm;
            int tg = t0 + tt;
            int co = i * 16 + quad * 4;
            short4 hv = *(const short4*)(hb + (size_t)tg * CH + co);
            short4 ho;
            ho.x = f2b((b2f(hv.x) + aR[i][j][0]) * scale);
            ho.y = f2b((b2f(hv.y) + aR[i][j][1]) * scale);
            ho.z = f2b((b2f(hv.z) + aR[i][j][2]) * scale);
            ho.w = f2b((b2f(hv.w) + aR[i][j][3]) * scale);
            *(short4*)(hob + (size_t)tg * CH + co) = ho;
            if (anyskip) {
                int ts = tg - LDIFF;
                if ((unsigned)ts < TPRIME) {
                    float4* sp = (float4*)(skb + (size_t)ts * CH + co);
                    float4 sv = *sp;
                    sv.x += aS[i][j][0]; sv.y += aS[i][j][1];
                    sv.z += aS[i][j][2]; sv.w += aS[i][j][3];
                    *sp = sv;
                }
            }
        }
}

// ---------------------------- skips fp32 [b][t'][c] -> relu -> bf16 (PROVEN r4)
__global__ __launch_bounds__(256) void k_skipcvt(const float* __restrict__ sk,
                                                 short* __restrict__ sbf) {
    int gid = blockIdx.x * 256 + threadIdx.x;
    size_t base = (size_t)gid * 4;
    float4 v = *(const float4*)(sk + base);
    short4 o;
    o.x = f2b(fmaxf(v.x, 0.f)); o.y = f2b(fmaxf(v.y, 0.f));
    o.z = f2b(fmaxf(v.z, 0.f)); o.w = f2b(fmaxf(v.w, 0.f));
    *(short4*)(sbf + base) = o;
}

// ---------------------------------------------------------------- fc1: halo-staged B, direct-global A
// y1 layout: [b][t'][2048] bf16, t' in [0,TPRIME)
__global__ __launch_bounds__(256) void k_fc1(const short* __restrict__ sbf,
                                             const short* __restrict__ Wp,  // [16][3][4][4][128][8]
                                             short* __restrict__ y1) {
    __shared__ __align__(16) short SB[17680];   // 130 rows x 17 int4 (pad) = 35.4 KB
    const int tid = threadIdx.x;
    const int l = tid & 63;
    const int w = tid >> 6;
    const int b = blockIdx.z;
    const int cob = blockIdx.y;
    const int t0 = blockIdx.x * 128;
    const int coq = (w & 1) * 64;
    const int tq = (w >> 1) * 64;
    const int lm = l & 15;
    const int quad = l >> 4;
    const short* sb = sbf + (size_t)b * TPRIME * CH;

    int4* Bl = (int4*)SB;
    for (int u = tid; u < 2080; u += 256) {
        int tt = u >> 4, kg = u & 15;
        int tg = t0 - 1 + tt;
        int4 v = make_int4(0, 0, 0, 0);
        if ((unsigned)tg < TPRIME)
            v = *(const int4*)(sb + (size_t)tg * CH + kg * 8);
        Bl[tt * 17 + kg] = v;
    }
    __syncthreads();

    const bf16x8* Wg = (const bf16x8*)Wp + (size_t)cob * 3 * 4 * 512;
    f32x4 acc[4][4] = {};
#pragma unroll
    for (int tap = 0; tap < 3; ++tap)
#pragma unroll
        for (int kc = 0; kc < 4; ++kc) {
            bf16x8 af[4], bfr[4];
#pragma unroll
            for (int i = 0; i < 4; ++i)
                af[i] = Wg[(tap * 4 + kc) * 512 + quad * 128 + coq + i * 16 + lm];
#pragma unroll
            for (int j = 0; j < 4; ++j)
                bfr[j] = *(const bf16x8*)(SB + ((tq + j * 16 + lm + tap) * 17 + kc * 4 + quad) * 8);
#pragma unroll
            for (int i = 0; i < 4; ++i)
#pragma unroll
                for (int j = 0; j < 4; ++j)
                    acc[i][j] = MFMA(af[i], bfr[j], acc[i][j]);
        }

    short* yb = y1 + (size_t)b * TPRIME * FC1C + cob * 128;
#pragma unroll
    for (int i = 0; i < 4; ++i)
#pragma unroll
        for (int j = 0; j < 4; ++j) {
            int tg = t0 + tq + j * 16 + lm;
            int co = coq + i * 16 + quad * 4;
            if ((unsigned)tg < TPRIME) {
                short4 v;
                v.x = f2b(fmaxf(acc[i][j][0], 0.f));
                v.y = f2b(fmaxf(acc[i][j][1], 0.f));
                v.z = f2b(fmaxf(acc[i][j][2], 0.f));
                v.w = f2b(fmaxf(acc[i][j][3], 0.f));
                *(short4*)(yb + (size_t)tg * FC1C + co) = v;
            }
        }
}

// ---------------------------------------------------------------- fc2: halo-staged B per 128-ci slice
__global__ __launch_bounds__(256) void k_fc2(const short* __restrict__ y1,
                                             const short* __restrict__ Wp,  // [2][3][64][4][128][8]
                                             const float* __restrict__ Wlast,
                                             float* __restrict__ out) {
    __shared__ __align__(16) short SB[17680];
    __shared__ float red[128];
    const int tid = threadIdx.x;
    const int l = tid & 63;
    const int w = tid >> 6;
    const int b = blockIdx.z;
    const int cob = blockIdx.y;
    const int t0 = blockIdx.x * 128;
    const int coq = (w & 1) * 64;
    const int tq = (w >> 1) * 64;
    const int lm = l & 15;
    const int quad = l >> 4;
    const short* yb = y1 + (size_t)b * TPRIME * FC1C;
    const bf16x8* Wg = (const bf16x8*)Wp;

    f32x4 acc[4][4] = {};
    for (int cic = 0; cic < 16; ++cic) {
        __syncthreads();
        int4* Bl = (int4*)SB;
        for (int u = tid; u < 2080; u += 256) {
            int tt = u >> 4, kg = u & 15;
            int tg = t0 - 1 + tt;
            int4 v = make_int4(0, 0, 0, 0);
            if ((unsigned)tg < TPRIME)
                v = *(const int4*)(yb + (size_t)tg * FC1C + cic * 128 + kg * 8);
            Bl[tt * 17 + kg] = v;
        }
        __syncthreads();
#pragma unroll
        for (int tap = 0; tap < 3; ++tap)
#pragma unroll
            for (int kc = 0; kc < 4; ++kc) {
                bf16x8 af[4], bfr[4];
#pragma unroll
                for (int i = 0; i < 4; ++i)
                    af[i] = Wg[((size_t)(cob * 3 + tap) * 64 + cic * 4 + kc) * 512 +
                               quad * 128 + coq + i * 16 + lm];
#pragma unroll
                for (int j = 0; j < 4; ++j)
                    bfr[j] = *(const bf16x8*)(SB + ((tq + j * 16 + lm + tap) * 17 + kc * 4 + quad) * 8);
#pragma unroll
                for (int i = 0; i < 4; ++i)
#pragma unroll
                    for (int j = 0; j < 4; ++j)
                        acc[i][j] = MFMA(af[i], bfr[j], acc[i][j]);
            }
    }

    // fused final 1x1 head (PROVEN r4)
    for (int r = tid; r < 128; r += 256) red[r] = 0.f;
    __syncthreads();
    float4 wv[4];
#pragma unroll
    for (int i = 0; i < 4; ++i)
        wv[i] = *(const float4*)(Wlast + cob * 128 + coq + i * 16 + quad * 4);
#pragma unroll
    for (int j = 0; j < 4; ++j) {
        float s = 0.f;
#pragma unroll
        for (int i = 0; i < 4; ++i)
            s += wv[i].x * acc[i][j][0] + wv[i].y * acc[i][j][1] +
                 wv[i].z * acc[i][j][2] + wv[i].w * acc[i][j][3];
        atomicAdd(&red[tq + j * 16 + lm], s);
    }
    __syncthreads();
    if (tid < 128) {
        int tg = t0 + tid;
        if (tg < TPRIME) atomicAdd(&out[(size_t)b * TPRIME + tg], red[tid]);
    }
}

// ---------------------------------------------------------------- bias init (PROVEN)
__global__ void k_bias(float* __restrict__ out, const float* __restrict__ bl) {
    int i = blockIdx.x * 256 + threadIdx.x;
    if (i < BATCH * TPRIME) out[i] = bl[0];
}

extern "C" void kernel_launch(void* const* d_in, const int* in_sizes, int n_in,
                              void* d_out, int out_size, void* d_ws, size_t ws_size,
                              hipStream_t stream) {
    const float* x = (const float*)d_in[0];
    const float* Wf = (const float*)d_in[1];
    const float* Wdil = (const float*)d_in[2];
    const float* Wskip = (const float*)d_in[3];
    const float* Wres = (const float*)d_in[4];
    const float* Wfc1 = (const float*)d_in[5];
    const float* Wfc2 = (const float*)d_in[6];
    const float* Wlast = (const float*)d_in[7];
    const float* blast = (const float*)d_in[8];
    float* out = (float*)d_out;

    char* p = (char*)d_ws;
    auto alloc = [&](size_t bytes) { char* r = p; p += (bytes + 255) & ~(size_t)255; return r; };
    float* skips = (float*)alloc((size_t)BATCH * TPRIME * CH * 4);   // 21.0 MB [b][t'][c]
    short* WpD   = (short*)alloc((size_t)NLAYERS * 49152 * 2);       // 2.95 MB
    short* Wsp   = (short*)alloc((size_t)NLAYERS * 8192 * 2);        // 0.49 MB
    short* Wrp   = (short*)alloc((size_t)NLAYERS * 8192 * 2);        // 0.49 MB
    short* Wp1   = (short*)alloc((size_t)786432 * 2);                // 1.5 MB
    short* Wp2   = (short*)alloc((size_t)1572864 * 2);               // 3.0 MB
    char*  big   = alloc((size_t)178362368);                         // 178.4 MB shared region
    short* hA  = (short*)big;                                        // layers: 16.78 MB
    short* hB  = (short*)(big + (size_t)BATCH * TLEN * CH * 2);      // layers: 16.78 MB
    short* sbf = (short*)big;                                        // head: 10.49 MB
    short* y1  = (short*)(big + (size_t)BATCH * TPRIME * CH * 2);    // head: 167.9 MB
    // total ~208 MB (ws_size = 256 MiB per harness poison WRITE_SIZE)

    k_prep_conv<<<5760, 256, 0, stream>>>(Wdil, WpD, 128, 4, 1474560);
    k_prep_conv<<<3072, 256, 0, stream>>>(Wfc1, Wp1, 128, 4, 786432);
    k_prep_conv<<<6144, 256, 0, stream>>>(Wfc2, Wp2, 2048, 64, 1572864);
    k_prep_sr<<<960, 256, 0, stream>>>(Wskip, Wres, Wsp, Wrp);
    hipMemsetAsync(skips, 0, (size_t)BATCH * TPRIME * CH * 4, stream);
    k_first<<<8192, 256, 0, stream>>>(x, Wf, hA);

    short* hin = hA;
    short* hout = hB;
    for (int lyr = 0; lyr < NLAYERS; ++lyr) {
        int d = 1 << (lyr % 10);
        k_layer<<<dim3(TLEN / 128, BATCH), 256, 0, stream>>>(
            hin, hout, skips, WpD + (size_t)lyr * 49152,
            Wsp + (size_t)lyr * 8192, Wrp + (size_t)lyr * 8192, d);
        short* tmp = hin; hin = hout; hout = tmp;
    }

    // h buffers dead; big region becomes sbf + y1
    k_skipcvt<<<5123, 256, 0, stream>>>(skips, sbf);
    k_bias<<<(BATCH * TPRIME + 255) / 256, 256, 0, stream>>>(out, blast);
    k_fc1<<<dim3(81, FC1C / 128, BATCH), 256, 0, stream>>>(sbf, Wp1, y1);
    k_fc2<<<dim3(81, FC2C / 128, BATCH), 256, 0, stream>>>(y1, Wp2, Wlast, out);
}

// Round 6
// 1482.155 us; speedup vs baseline: 7.3631x; 1.2456x over previous
//
#include <hip/hip_runtime.h>
#include <hip/hip_bf16.h>

#define BATCH 4
#define TLEN 16384
#define CH 128
#define HC 64
#define TPRIME 10246
#define LDIFF 3069
#define NLAYERS 30
#define FC1C 2048
#define FC2C 256

typedef short bf16x8 __attribute__((ext_vector_type(8)));
typedef float f32x4 __attribute__((ext_vector_type(4)));
#define MFMA(a, b, c) __builtin_amdgcn_mfma_f32_16x16x32_bf16(a, b, c, 0, 0, 0)

static __device__ __forceinline__ short f2b(float f) {
    __hip_bfloat16 h = __float2bfloat16(f);
    return *reinterpret_cast<short*>(&h);
}
static __device__ __forceinline__ float b2f(short s) {
    __hip_bfloat16 h;
    *reinterpret_cast<short*>(&h) = s;
    return __bfloat162float(h);
}

// ---------------------------------------------------------------- MFMA weight packer (PROVEN r3/r4)
// out layout: [cob][tap][kc][kg(4)][co(128)][j(8)]  (bf16), ci = kc*32+kg*8+j
__global__ void k_prep_conv(const float* __restrict__ W, short* __restrict__ Wp,
                            int CIN, int KC, int total) {
    int o = blockIdx.x * 256 + threadIdx.x;
    if (o >= total) return;
    int j = o & 7;
    int co = (o >> 3) & 127;
    int kg = (o >> 10) & 3;
    int rest = o >> 12;       // = (cob*3+tap)*KC + kc
    int kc = rest % KC;
    int ct = rest / KC;
    int tap = ct % 3;
    int cob = ct / 3;
    int ci = kc * 32 + kg * 8 + j;
    int cog = cob * 128 + co;
    Wp[o] = f2b(W[((size_t)cog * CIN + ci) * 3 + tap]);
}

// skip/res 1x1 weights: out [layer][kg(8)][co(128)][j(8)], cz = kg*8+j (PROVEN r4)
__global__ void k_prep_sr(const float* __restrict__ Ws, const float* __restrict__ Wr,
                          short* __restrict__ Wsp, short* __restrict__ Wrp) {
    int o = blockIdx.x * 256 + threadIdx.x;
    if (o >= NLAYERS * 8192) return;
    int j = o & 7;
    int co = (o >> 3) & 127;
    int kg = (o >> 10) & 7;
    int lay = o >> 13;
    size_t in = ((size_t)lay * 128 + co) * 64 + kg * 8 + j;
    Wsp[o] = f2b(Ws[in]);
    Wrp[o] = f2b(Wr[in]);
}

// ---------------------------------------------------------------- first conv -> h[b][t][c] bf16 (PROVEN r4)
__global__ __launch_bounds__(256) void k_first(const float* __restrict__ x,
                                               const float* __restrict__ Wf,
                                               short* __restrict__ h) {
    int gid = blockIdx.x * 256 + threadIdx.x;   // B*T*32 units of 4 co
    int co4 = (gid & 31) * 4;
    int t = (gid >> 5) & (TLEN - 1);
    int b = gid >> 19;
    const float* xb = x + (size_t)b * TLEN;
    float xm = t > 0 ? xb[t - 1] : 0.f;
    float x0 = xb[t];
    float xp = t < TLEN - 1 ? xb[t + 1] : 0.f;
    short4 o;
    float r[4];
#pragma unroll
    for (int i = 0; i < 4; ++i) {
        const float* wp = Wf + (co4 + i) * 3;
        r[i] = wp[0] * xm + wp[1] * x0 + wp[2] * xp;
    }
    o.x = f2b(r[0]); o.y = f2b(r[1]); o.z = f2b(r[2]); o.w = f2b(r[3]);
    *(short4*)(h + (size_t)b * TLEN * CH + (size_t)t * CH + co4) = o;
}

// ---------------------------------------------------------------- layer kernel (barrier-free conv)
// Conv A AND B fragments read direct from global (h is [t][c]: a B fragment is a
// contiguous 16B chunk; reuse = 8 MFMA per load; h is L2/L3-resident). Zero
// barriers in the conv loop. GLU in-register; z via 16KB LDS (1 barrier);
// skip/res weights direct from global.
__global__ __launch_bounds__(256) void k_layer(
    const short* __restrict__ hin, short* __restrict__ hout,
    float* __restrict__ skips,              // [b][t'][c] fp32
    const short* __restrict__ Wp,           // [3][4][4][128][8] this layer
    const short* __restrict__ Wsp,          // [8][128][8] this layer
    const short* __restrict__ Wrp,
    int d) {
    __shared__ __align__(16) short SZ[8192];  // z: [kg8][tt128][j8] = 16 KB
    const int tid = threadIdx.x;
    const int l = tid & 63;
    const int w = tid >> 6;
    const int lm = l & 15;
    const int quad = l >> 4;
    const int b = blockIdx.y;
    const int t0 = blockIdx.x * 128;
    const int tq = w * 32;
    const short* hb = hin + (size_t)b * TLEN * CH;
    const bf16x8* Wg = (const bf16x8*)Wp;

    f32x4 acc[8][2] = {};
    for (int tap = 0; tap < 3; ++tap) {
        const int toff = (tap - 1) * d;
#pragma unroll
        for (int kc = 0; kc < 4; ++kc) {
            bf16x8 af[8], bfr[2];
#pragma unroll
            for (int i = 0; i < 8; ++i)
                af[i] = Wg[(tap * 4 + kc) * 512 + quad * 128 + i * 16 + lm];
#pragma unroll
            for (int j = 0; j < 2; ++j) {
                int tg = t0 + tq + j * 16 + lm + toff;
                bf16x8 v = {};
                if ((unsigned)tg < TLEN)
                    v = *(const bf16x8*)(hb + (size_t)tg * CH + kc * 32 + quad * 8);
                bfr[j] = v;
            }
#pragma unroll
            for (int i = 0; i < 8; ++i)
#pragma unroll
                for (int j = 0; j < 2; ++j)
                    acc[i][j] = MFMA(af[i], bfr[j], acc[i][j]);
        }
    }

    // ---- GLU in-register (fp32), write z to LDS in B-operand layout (PROVEN r4/r5)
#pragma unroll
    for (int i = 0; i < 4; ++i)
#pragma unroll
        for (int j = 0; j < 2; ++j) {
            short zo[4];
#pragma unroll
            for (int r = 0; r < 4; ++r) {
                float a = acc[i][j][r];        // co = i*16+quad*4+r  (filter)
                float g = acc[i + 4][j][r];    // co + 64             (gate)
                float th = tanhf(a);
                float sg = 1.f / (1.f + __expf(-g));
                zo[r] = f2b(th * sg);
            }
            int co = i * 16 + quad * 4;        // cz in [0,64)
            int kg = co >> 3;
            int jj0 = co & 7;                  // 0 or 4
            short4 zv = {zo[0], zo[1], zo[2], zo[3]};
            *(short4*)(SZ + (kg * 128 + tq + j * 16 + lm) * 8 + jj0) = zv;
        }
    __syncthreads();

    // ---- skip/res GEMMs, K=64; weights direct from global (L2) (PROVEN r5)
    const bf16x8* Wsg = (const bf16x8*)Wsp;
    const bf16x8* Wrg = (const bf16x8*)Wrp;
    f32x4 aS[8][2] = {}, aR[8][2] = {};
#pragma unroll
    for (int kk = 0; kk < 2; ++kk) {
        int kgg = kk * 4 + quad;
        bf16x8 zs[2], wsf[8], wrf[8];
#pragma unroll
        for (int j = 0; j < 2; ++j)
            zs[j] = *(const bf16x8*)(SZ + (kgg * 128 + tq + j * 16 + lm) * 8);
#pragma unroll
        for (int i = 0; i < 8; ++i) {
            wsf[i] = Wsg[kgg * 128 + i * 16 + lm];
            wrf[i] = Wrg[kgg * 128 + i * 16 + lm];
        }
#pragma unroll
        for (int i = 0; i < 8; ++i)
#pragma unroll
            for (int j = 0; j < 2; ++j) {
                aS[i][j] = MFMA(wsf[i], zs[j], aS[i][j]);
                aR[i][j] = MFMA(wrf[i], zs[j], aR[i][j]);
            }
    }

    const float scale = 0.70710678118654752f;
    short* hob = hout + (size_t)b * TLEN * CH;
    float* skb = skips + (size_t)b * TPRIME * CH;
    const bool anyskip = (t0 + 127 >= LDIFF) && (t0 < LDIFF + TPRIME);
#pragma unroll
    for (int i = 0; i < 8; ++i)
#pragma unroll
        for (int j = 0; j < 2; ++j) {
            int tt = tq + j * 16 + lm;
            int tg = t0 + tt;
            int co = i * 16 + quad * 4;
            short4 hv = *(const short4*)(hb + (size_t)tg * CH + co);
            short4 ho;
            ho.x = f2b((b2f(hv.x) + aR[i][j][0]) * scale);
            ho.y = f2b((b2f(hv.y) + aR[i][j][1]) * scale);
            ho.z = f2b((b2f(hv.z) + aR[i][j][2]) * scale);
            ho.w = f2b((b2f(hv.w) + aR[i][j][3]) * scale);
            *(short4*)(hob + (size_t)tg * CH + co) = ho;
            if (anyskip) {
                int ts = tg - LDIFF;
                if ((unsigned)ts < TPRIME) {
                    float4* sp = (float4*)(skb + (size_t)ts * CH + co);
                    float4 sv = *sp;
                    sv.x += aS[i][j][0]; sv.y += aS[i][j][1];
                    sv.z += aS[i][j][2]; sv.w += aS[i][j][3];
                    *sp = sv;
                }
            }
        }
}

// ---------------------------- skips fp32 [b][t'][c] -> relu -> bf16 (PROVEN r4)
__global__ __launch_bounds__(256) void k_skipcvt(const float* __restrict__ sk,
                                                 short* __restrict__ sbf) {
    int gid = blockIdx.x * 256 + threadIdx.x;
    size_t base = (size_t)gid * 4;
    float4 v = *(const float4*)(sk + base);
    short4 o;
    o.x = f2b(fmaxf(v.x, 0.f)); o.y = f2b(fmaxf(v.y, 0.f));
    o.z = f2b(fmaxf(v.z, 0.f)); o.w = f2b(fmaxf(v.w, 0.f));
    *(short4*)(sbf + base) = o;
}

// ---------------------------------------------------------------- fc1 (PROVEN r5)
__global__ __launch_bounds__(256) void k_fc1(const short* __restrict__ sbf,
                                             const short* __restrict__ Wp,  // [16][3][4][4][128][8]
                                             short* __restrict__ y1) {
    __shared__ __align__(16) short SB[17680];   // 130 rows x 17 int4 (pad)
    const int tid = threadIdx.x;
    const int l = tid & 63;
    const int w = tid >> 6;
    const int b = blockIdx.z;
    const int cob = blockIdx.y;
    const int t0 = blockIdx.x * 128;
    const int coq = (w & 1) * 64;
    const int tq = (w >> 1) * 64;
    const int lm = l & 15;
    const int quad = l >> 4;
    const short* sb = sbf + (size_t)b * TPRIME * CH;

    int4* Bl = (int4*)SB;
    for (int u = tid; u < 2080; u += 256) {
        int tt = u >> 4, kg = u & 15;
        int tg = t0 - 1 + tt;
        int4 v = make_int4(0, 0, 0, 0);
        if ((unsigned)tg < TPRIME)
            v = *(const int4*)(sb + (size_t)tg * CH + kg * 8);
        Bl[tt * 17 + kg] = v;
    }
    __syncthreads();

    const bf16x8* Wg = (const bf16x8*)Wp + (size_t)cob * 3 * 4 * 512;
    f32x4 acc[4][4] = {};
#pragma unroll
    for (int tap = 0; tap < 3; ++tap)
#pragma unroll
        for (int kc = 0; kc < 4; ++kc) {
            bf16x8 af[4], bfr[4];
#pragma unroll
            for (int i = 0; i < 4; ++i)
                af[i] = Wg[(tap * 4 + kc) * 512 + quad * 128 + coq + i * 16 + lm];
#pragma unroll
            for (int j = 0; j < 4; ++j)
                bfr[j] = *(const bf16x8*)(SB + ((tq + j * 16 + lm + tap) * 17 + kc * 4 + quad) * 8);
#pragma unroll
            for (int i = 0; i < 4; ++i)
#pragma unroll
                for (int j = 0; j < 4; ++j)
                    acc[i][j] = MFMA(af[i], bfr[j], acc[i][j]);
        }

    short* yb = y1 + (size_t)b * TPRIME * FC1C + cob * 128;
#pragma unroll
    for (int i = 0; i < 4; ++i)
#pragma unroll
        for (int j = 0; j < 4; ++j) {
            int tg = t0 + tq + j * 16 + lm;
            int co = coq + i * 16 + quad * 4;
            if ((unsigned)tg < TPRIME) {
                short4 v;
                v.x = f2b(fmaxf(acc[i][j][0], 0.f));
                v.y = f2b(fmaxf(acc[i][j][1], 0.f));
                v.z = f2b(fmaxf(acc[i][j][2], 0.f));
                v.w = f2b(fmaxf(acc[i][j][3], 0.f));
                *(short4*)(yb + (size_t)tg * FC1C + co) = v;
            }
        }
}

// ---------------------------------------------------------------- fc2: K-split x4, reg-prefetch dbuf,
// conflict-free [kg][tt] LDS layout, A direct-global, fused 1x1 head via atomics.
__global__ __launch_bounds__(256) void k_fc2(const short* __restrict__ y1,
                                             const short* __restrict__ Wp,  // [2][3][64][4][128][8]
                                             const float* __restrict__ Wlast,
                                             float* __restrict__ out) {
    __shared__ __align__(16) short SB[16640];   // [kg16][tt130][j8] = 33.3 KB
    __shared__ float red[128];
    const int tid = threadIdx.x;
    const int l = tid & 63;
    const int w = tid >> 6;
    const int bz = blockIdx.z;          // = b*4 + ks
    const int b = bz >> 2;
    const int ks = bz & 3;
    const int cob = blockIdx.y;
    const int t0 = blockIdx.x * 128;
    const int coq = (w & 1) * 64;
    const int tq = (w >> 1) * 64;
    const int lm = l & 15;
    const int quad = l >> 4;
    const short* yb = y1 + (size_t)b * TPRIME * FC1C;
    const bf16x8* Wg = (const bf16x8*)Wp;

    int4 pre[9];
    const int cic0 = ks * 4;
    // prefetch slice cic0 into registers
#pragma unroll
    for (int r = 0; r < 9; ++r) {
        int u = r * 256 + tid;
        if (u < 2080) {
            int kg = u / 130, tt = u - kg * 130;
            int tg = t0 - 1 + tt;
            int4 v = make_int4(0, 0, 0, 0);
            if ((unsigned)tg < TPRIME)
                v = *(const int4*)(yb + (size_t)tg * FC1C + cic0 * 128 + kg * 8);
            pre[r] = v;
        }
    }

    f32x4 acc[4][4] = {};
    for (int ci = 0; ci < 4; ++ci) {
        const int cic = cic0 + ci;
        __syncthreads();              // prior SB reads complete
        int4* Bl = (int4*)SB;
#pragma unroll
        for (int r = 0; r < 9; ++r) {
            int u = r * 256 + tid;
            if (u < 2080) Bl[u] = pre[r];
        }
        if (ci < 3) {                 // prefetch next slice; overlaps MFMA below
#pragma unroll
            for (int r = 0; r < 9; ++r) {
                int u = r * 256 + tid;
                if (u < 2080) {
                    int kg = u / 130, tt = u - kg * 130;
                    int tg = t0 - 1 + tt;
                    int4 v = make_int4(0, 0, 0, 0);
                    if ((unsigned)tg < TPRIME)
                        v = *(const int4*)(yb + (size_t)tg * FC1C + (cic + 1) * 128 + kg * 8);
                    pre[r] = v;
                }
            }
        }
        __syncthreads();
#pragma unroll
        for (int tap = 0; tap < 3; ++tap)
#pragma unroll
            for (int kc = 0; kc < 4; ++kc) {
                bf16x8 af[4], bfr[4];
#pragma unroll
                for (int i = 0; i < 4; ++i)
                    af[i] = Wg[((size_t)(cob * 3 + tap) * 64 + cic * 4 + kc) * 512 +
                               quad * 128 + coq + i * 16 + lm];
#pragma unroll
                for (int j = 0; j < 4; ++j)
                    bfr[j] = *(const bf16x8*)(SB + ((kc * 4 + quad) * 130 + tq + j * 16 + lm + tap) * 8);
#pragma unroll
                for (int i = 0; i < 4; ++i)
#pragma unroll
                    for (int j = 0; j < 4; ++j)
                        acc[i][j] = MFMA(af[i], bfr[j], acc[i][j]);
            }
    }

    // fused final 1x1 head (PROVEN r4/r5); each K-split block adds its partial
    for (int r = tid; r < 128; r += 256) red[r] = 0.f;
    __syncthreads();
    float4 wv[4];
#pragma unroll
    for (int i = 0; i < 4; ++i)
        wv[i] = *(const float4*)(Wlast + cob * 128 + coq + i * 16 + quad * 4);
#pragma unroll
    for (int j = 0; j < 4; ++j) {
        float s = 0.f;
#pragma unroll
        for (int i = 0; i < 4; ++i)
            s += wv[i].x * acc[i][j][0] + wv[i].y * acc[i][j][1] +
                 wv[i].z * acc[i][j][2] + wv[i].w * acc[i][j][3];
        atomicAdd(&red[tq + j * 16 + lm], s);
    }
    __syncthreads();
    if (tid < 128) {
        int tg = t0 + tid;
        if (tg < TPRIME) atomicAdd(&out[(size_t)b * TPRIME + tg], red[tid]);
    }
}

// ---------------------------------------------------------------- bias init (PROVEN)
__global__ void k_bias(float* __restrict__ out, const float* __restrict__ bl) {
    int i = blockIdx.x * 256 + threadIdx.x;
    if (i < BATCH * TPRIME) out[i] = bl[0];
}

extern "C" void kernel_launch(void* const* d_in, const int* in_sizes, int n_in,
                              void* d_out, int out_size, void* d_ws, size_t ws_size,
                              hipStream_t stream) {
    const float* x = (const float*)d_in[0];
    const float* Wf = (const float*)d_in[1];
    const float* Wdil = (const float*)d_in[2];
    const float* Wskip = (const float*)d_in[3];
    const float* Wres = (const float*)d_in[4];
    const float* Wfc1 = (const float*)d_in[5];
    const float* Wfc2 = (const float*)d_in[6];
    const float* Wlast = (const float*)d_in[7];
    const float* blast = (const float*)d_in[8];
    float* out = (float*)d_out;

    char* p = (char*)d_ws;
    auto alloc = [&](size_t bytes) { char* r = p; p += (bytes + 255) & ~(size_t)255; return r; };
    float* skips = (float*)alloc((size_t)BATCH * TPRIME * CH * 4);   // 21.0 MB [b][t'][c]
    short* WpD   = (short*)alloc((size_t)NLAYERS * 49152 * 2);       // 2.95 MB
    short* Wsp   = (short*)alloc((size_t)NLAYERS * 8192 * 2);        // 0.49 MB
    short* Wrp   = (short*)alloc((size_t)NLAYERS * 8192 * 2);        // 0.49 MB
    short* Wp1   = (short*)alloc((size_t)786432 * 2);                // 1.5 MB
    short* Wp2   = (short*)alloc((size_t)1572864 * 2);               // 3.0 MB
    char*  big   = alloc((size_t)178362368);                         // 178.4 MB shared region
    short* hA  = (short*)big;                                        // layers: 16.78 MB
    short* hB  = (short*)(big + (size_t)BATCH * TLEN * CH * 2);      // layers: 16.78 MB
    short* sbf = (short*)big;                                        // head: 10.49 MB
    short* y1  = (short*)(big + (size_t)BATCH * TPRIME * CH * 2);    // head: 167.9 MB

    k_prep_conv<<<5760, 256, 0, stream>>>(Wdil, WpD, 128, 4, 1474560);
    k_prep_conv<<<3072, 256, 0, stream>>>(Wfc1, Wp1, 128, 4, 786432);
    k_prep_conv<<<6144, 256, 0, stream>>>(Wfc2, Wp2, 2048, 64, 1572864);
    k_prep_sr<<<960, 256, 0, stream>>>(Wskip, Wres, Wsp, Wrp);
    hipMemsetAsync(skips, 0, (size_t)BATCH * TPRIME * CH * 4, stream);
    k_first<<<8192, 256, 0, stream>>>(x, Wf, hA);

    short* hin = hA;
    short* hout = hB;
    for (int lyr = 0; lyr < NLAYERS; ++lyr) {
        int d = 1 << (lyr % 10);
        k_layer<<<dim3(TLEN / 128, BATCH), 256, 0, stream>>>(
            hin, hout, skips, WpD + (size_t)lyr * 49152,
            Wsp + (size_t)lyr * 8192, Wrp + (size_t)lyr * 8192, d);
        short* tmp = hin; hin = hout; hout = tmp;
    }

    // h buffers dead; big region becomes sbf + y1
    k_skipcvt<<<5123, 256, 0, stream>>>(skips, sbf);
    k_bias<<<(BATCH * TPRIME + 255) / 256, 256, 0, stream>>>(out, blast);
    k_fc1<<<dim3(81, FC1C / 128, BATCH), 256, 0, stream>>>(sbf, Wp1, y1);
    k_fc2<<<dim3(81, FC2C / 128, BATCH * 4), 256, 0, stream>>>(y1, Wp2, Wlast, out);
}